// Round 11
// baseline (1950.005 us; speedup 1.0000x reference)
//
#include <hip/hip_runtime.h>
#include <hip/hip_bf16.h>

#define B_    8
#define N_    4096
#define D_    64
#define NP_   1024
#define K_    32
#define NC_   212
#define CO_   128
#define SVW   72
#define PUB   16    // fps publish granularity (samples)

// f32 ops with guaranteed IEEE rounding, no FMA contraction — match numpy f32 bit-exactly.
__device__ __forceinline__ float f32add(float a, float b) { return __fadd_rn(a, b); }
__device__ __forceinline__ float f32sub(float a, float b) { return __fsub_rn(a, b); }
__device__ __forceinline__ float f32mul(float a, float b) { return __fmul_rn(a, b); }

// Wave64 argmax via DPP directional reduce; merge = (max val, min idx) == np.argmax.
__device__ __forceinline__ void waveArgmaxDpp(float& best, int& bidx) {
#define AMAX_STEP(CTRL)                                                                     \
    {                                                                                       \
        int _v = __builtin_amdgcn_update_dpp(__float_as_int(best), __float_as_int(best),    \
                                             (CTRL), 0xf, 0xf, false);                      \
        int _i = __builtin_amdgcn_update_dpp(bidx, bidx, (CTRL), 0xf, 0xf, false);          \
        float _f = __int_as_float(_v);                                                      \
        if (_f > best || (_f == best && _i < bidx)) { best = _f; bidx = _i; }               \
    }
    AMAX_STEP(0x111); AMAX_STEP(0x112); AMAX_STEP(0x114);
    AMAX_STEP(0x118); AMAX_STEP(0x142); AMAX_STEP(0x143);
#undef AMAX_STEP
    best = __int_as_float(__builtin_amdgcn_readlane(__float_as_int(best), 63));
    bidx = __builtin_amdgcn_readlane(bidx, 63);
}

struct FpsSm {
    float X[N_], Y[N_], Z[N_];
    int   hist[NP_];
    float redV[2][4];
    int   redI[2][4];
};
struct FusedSm {
    float sV[K_][SVW];
    float sF[68];
    float sFD[K_];
    float sGD[3];
    float sGsum[3];
    float sPool[NC_];
    int   sNb[K_];
    int   sCnt;
};
union MegaSm { FpsSm f; FusedSm u; };

// ---------------------------------------------------------------------------
// FPS role: one block (4 waves) per batch. Math bit-identical to the proven
// round-6..10 kernel. Publishes fpsIdx/new_xyz every PUB samples with a
// device-scope release on progress[b] so fused blocks can start immediately.
// ---------------------------------------------------------------------------
__device__ __forceinline__ void fps_role(
    int b, const float* __restrict__ xyz, int* fpsIdx, float* out0,
    int* progress, FpsSm& sm) {
    const float* P = xyz + (size_t)b * N_ * 3;
    int tid = threadIdx.x;
    for (int i = tid; i < N_; i += 256) {
        sm.X[i] = P[i * 3 + 0];
        sm.Y[i] = P[i * 3 + 1];
        sm.Z[i] = P[i * 3 + 2];
    }
    if (tid == 0) sm.hist[0] = 0;
    __syncthreads();

    const int PPT = N_ / 256;  // 16
    float px[PPT], py[PPT], pz[PPT], dist[PPT];
#pragma unroll
    for (int c = 0; c < PPT; c++) {
        int j = tid + 256 * c;
        px[c] = sm.X[j]; py[c] = sm.Y[j]; pz[c] = sm.Z[j];
        dist[c] = 1e10f;
    }
    int last = 0;
    for (int it = 1; it < NP_; ++it) {
        float lx = sm.X[last], ly = sm.Y[last], lz = sm.Z[last];
        float best = -1.0f; int bidx = 0;
#pragma unroll
        for (int c = 0; c < PPT; c++) {
            float dx = f32sub(px[c], lx), dy = f32sub(py[c], ly), dz = f32sub(pz[c], lz);
            float nd = f32add(f32add(f32mul(dx, dx), f32mul(dy, dy)), f32mul(dz, dz));
            float d  = fminf(dist[c], nd);
            dist[c] = d;
            if (d > best) { best = d; bidx = tid + 256 * c; }   // ties: lowest j
        }
        waveArgmaxDpp(best, bidx);
        int par = it & 1;
        if ((tid & 63) == 0) { sm.redV[par][tid >> 6] = best; sm.redI[par][tid >> 6] = bidx; }
        __syncthreads();
        float bv = sm.redV[par][0]; int bi = sm.redI[par][0];
#pragma unroll
        for (int w = 1; w < 4; w++) {
            float ov = sm.redV[par][w]; int oi = sm.redI[par][w];
            if (ov > bv || (ov == bv && oi < bi)) { bv = ov; bi = oi; }
        }
        last = bi;
        if (tid == 0) sm.hist[it] = last;

        // publish samples [it-PUB, it) — hist entries all barrier-protected
        if ((it & (PUB - 1)) == 0) {
            if (tid < PUB) {
                int s = it - PUB + tid;
                int j = sm.hist[s];
                fpsIdx[b * NP_ + s] = j;
                size_t o = (size_t)(b * NP_ + s) * 3;
                out0[o + 0] = sm.X[j]; out0[o + 1] = sm.Y[j]; out0[o + 2] = sm.Z[j];
            }
            if (tid == 0) {   // tid0-15 are one wave: vmcnt covers their stores
                __threadfence();
                __hip_atomic_store(&progress[b], it, __ATOMIC_RELEASE,
                                   __HIP_MEMORY_SCOPE_AGENT);
            }
        }
    }
    __syncthreads();   // make hist[1008..1023] visible
    if (tid < PUB) {
        int s = NP_ - PUB + tid;
        int j = sm.hist[s];
        fpsIdx[b * NP_ + s] = j;
        size_t o = (size_t)(b * NP_ + s) * 3;
        out0[o + 0] = sm.X[j]; out0[o + 1] = sm.Y[j]; out0[o + 2] = sm.Z[j];
    }
    if (tid == 0) {
        __threadfence();
        __hip_atomic_store(&progress[b], NP_, __ATOMIC_RELEASE, __HIP_MEMORY_SCOPE_AGENT);
    }
}

// ---------------------------------------------------------------------------
// Fused role: identical math to the passing round-8..10 fused kernel;
// waits (acquire) for its sample, reads fpsIdx/new_xyz via agent atomics.
// ---------------------------------------------------------------------------
__device__ __forceinline__ void fused_role(
    int q, const float* __restrict__ feat, const float* __restrict__ xyz,
    const float* newxyz, const int* fpsIdx, int* progress,
    const float* __restrict__ A, const float* __restrict__ W1,
    const float* __restrict__ B1, float* __restrict__ out1, FusedSm& sm) {
    int b = q >> 10, n = q & (NP_ - 1);
    int tid = threadIdx.x;

    // wait until fps sample n of batch b is published
    while (__hip_atomic_load(&progress[b], __ATOMIC_ACQUIRE, __HIP_MEMORY_SCOPE_AGENT) <= n)
        __builtin_amdgcn_s_sleep(32);
    __syncthreads();

    int   fj = __hip_atomic_load(&fpsIdx[q], __ATOMIC_RELAXED, __HIP_MEMORY_SCOPE_AGENT);
    float qx = __hip_atomic_load(&newxyz[q * 3 + 0], __ATOMIC_RELAXED, __HIP_MEMORY_SCOPE_AGENT);
    float qy = __hip_atomic_load(&newxyz[q * 3 + 1], __ATOMIC_RELAXED, __HIP_MEMORY_SCOPE_AGENT);
    float qz = __hip_atomic_load(&newxyz[q * 3 + 2], __ATOMIC_RELAXED, __HIP_MEMORY_SCOPE_AGENT);

    // ph0: f gather + g; wave 0 does ball query (proven-exact f32 math)
    if (tid < D_) sm.sF[tid] = feat[((size_t)b * D_ + tid) * N_ + fj];
    if (tid >= D_ && tid < D_ + 3) sm.sF[tid] = (tid == D_) ? qx : (tid == D_ + 1 ? qy : qz);

    if (tid < 64) {
        int lane = tid;
        if (lane < K_) sm.sNb[lane] = N_ - 1;   // empty-ball fallback
        const float* P = xyz + (size_t)b * N_ * 3;
        float sq = f32add(f32add(f32mul(qx, qx), f32mul(qy, qy)), f32mul(qz, qz));
        const float R2 = (float)(0.2 * 0.2);
        int count = 0;
        for (int base = 0; base < N_ && count < K_; base += 64) {
            int j = base + lane;
            float x = P[j * 3 + 0];
            float y = P[j * 3 + 1];
            float z = P[j * 3 + 2];
            float sxj = f32add(f32add(f32mul(x, x), f32mul(y, y)), f32mul(z, z));
            float dot = __fmaf_rn(qz, z, __fmaf_rn(qy, y, __fmul_rn(qx, x)));
            float d2  = f32sub(f32add(sq, sxj), f32mul(2.0f, dot));
            bool in = (d2 <= R2);
            unsigned long long m = __ballot(in);
            if (in) {
                int pos = count + __popcll(m & ((1ull << lane) - 1ull));
                if (pos < K_) sm.sNb[pos] = j;
            }
            count += __popcll(m);
        }
        if (lane == 0) sm.sCnt = (count < K_) ? count : K_;
    }
    __syncthreads();
    int cnt = sm.sCnt;

    // ph1: fn -> sV[k][4..67]; raw gn -> sV[k][0..2]; zero pad cols 69..71
    {
        int k = tid >> 3, l = tid & 7;
        int j = (k < cnt || cnt == 0) ? sm.sNb[k] : sm.sNb[0];
        const float* src = feat + (size_t)b * D_ * N_ + j;
#pragma unroll
        for (int dd = 0; dd < 8; dd++) {
            int d = l * 8 + dd;
            sm.sV[k][4 + d] = src[(size_t)d * N_];
        }
    }
    if (tid < 96) {
        int k = tid / 3, c = tid % 3;
        int j = (k < cnt || cnt == 0) ? sm.sNb[k] : sm.sNb[0];
        sm.sV[k][c] = xyz[((size_t)b * N_ + j) * 3 + c];
        sm.sV[k][69 + c] = 0.f;
    }
    __syncthreads();

    // ph2: fdist per neighbor (8-thread groups)
    {
        int k = tid >> 3, ds = (tid & 7) * 8;
        float s = 0.f;
#pragma unroll
        for (int j = 0; j < 8; j++) s += fabsf(sm.sF[ds + j] - sm.sV[k][4 + ds + j]);
        s += __shfl_xor(s, 1); s += __shfl_xor(s, 2); s += __shfl_xor(s, 4);
        if ((tid & 7) == 0) sm.sFD[k] = __expf(-s * (1.0f / 64.0f));
    }
    __syncthreads();

    // ph3a: scale gn in place -> gnf
    if (tid < 96) {
        int k = tid / 3, c = tid % 3;
        sm.sV[k][c] = sm.sV[k][c] * sm.sFD[k];
    }
    __syncthreads();

    // ph3b: dg per k; gsum per c
    if (tid < K_) {
        int k = tid;
        float a0 = sm.sF[64] - sm.sV[k][0], a1 = sm.sF[65] - sm.sV[k][1], a2 = sm.sF[66] - sm.sV[k][2];
        sm.sV[k][3] = sqrtf(a0 * a0 + a1 * a1 + a2 * a2);
    }
    if (tid >= 64 && tid < 67) {
        int c = tid - 64;
        float s = 0.f;
        for (int k = 0; k < K_; k++) s += sm.sV[k][c];
        sm.sGsum[c] = s;
    }
    __syncthreads();

    // ph3c: gd
    if (tid == 0) {
        float m0 = sm.sGsum[0] * (1.f / K_), m1 = sm.sGsum[1] * (1.f / K_), m2 = sm.sGsum[2] * (1.f / K_);
        float mm = fmaxf(m0, fmaxf(m1, m2));
        float e0 = __expf(m0 - mm), e1 = __expf(m1 - mm), e2 = __expf(m2 - mm);
        float inv = 1.f / (e0 + e1 + e2);
        float g0 = sm.sF[64], g1 = sm.sF[65], g2 = sm.sF[66];
        float gm = fmaxf(g0, fmaxf(g1, g2));
        float f0 = __expf(g0 - gm), f1 = __expf(g1 - gm), f2 = __expf(g2 - gm);
        float inv2 = 1.f / (f0 + f1 + f2);
        sm.sGD[0] = fabsf(e0 * inv - f0 * inv2);
        sm.sGD[1] = fabsf(e1 * inv - f1 * inv2);
        sm.sGD[2] = fabsf(e2 * inv - f2 * inv2);
    }
    __syncthreads();

    // ph4: df per k (8-thread groups over the 67 pf1 entries)
    {
        int k = tid >> 3, l = tid & 7;
        float s = 0.f;
        for (int c = l; c < 67; c += 8) {
            float v = (c < D_) ? (sm.sF[c] - sm.sV[k][4 + c]) : (sm.sF[c] - sm.sGD[c - D_]);
            s += v * v;
        }
        s += __shfl_xor(s, 1); s += __shfl_xor(s, 2); s += __shfl_xor(s, 4);
        if (l == 0) sm.sV[k][68] = sqrtf(s);
    }
    __syncthreads();

    // ph5: e = leaky(base + q.var); softmax over k; pooled
    if (tid < NC_) {
        const float* Ac = A + tid;
        float g0 = sm.sF[64], g1 = sm.sF[65], g2 = sm.sF[66];
        float base = 0.f;
        base += Ac[(size_t)3 * NC_] * g0 + Ac[(size_t)4 * NC_] * g1 + Ac[(size_t)5 * NC_] * g2;
#pragma unroll 4
        for (int i = 0; i < 67; i++) base += Ac[(size_t)(77 + i) * NC_] * sm.sF[i];
#pragma unroll
        for (int j = 0; j < 3; j++) {
            float gdj = sm.sGD[j], gj = sm.sF[64 + j];
            base += Ac[(size_t)(74 + j) * NC_] * gdj + Ac[(size_t)(208 + j) * NC_] * (gj - gdj);
        }
#pragma unroll 4
        for (int i = 0; i < D_; i++) base += Ac[(size_t)(144 + i) * NC_] * sm.sF[i];

        float acc[K_];
#pragma unroll
        for (int k = 0; k < K_; k++) acc[k] = 0.f;

        {
            float q0 = Ac[0] - Ac[(size_t)6 * NC_];
            float q1 = Ac[(size_t)1 * NC_] - Ac[(size_t)7 * NC_];
            float q2 = Ac[(size_t)2 * NC_] - Ac[(size_t)8 * NC_];
            float q3 = Ac[(size_t)9 * NC_];
#pragma unroll
            for (int k = 0; k < K_; k++) {
                float4 v = *(const float4*)&sm.sV[k][0];
                acc[k] = fmaf(v.x, q0, fmaf(v.y, q1, fmaf(v.z, q2, fmaf(v.w, q3, acc[k]))));
            }
        }
        for (int gi = 0; gi < 16; gi++) {
            int i0 = gi * 4;
            float q0 = Ac[(size_t)(10 + i0 + 0) * NC_] - Ac[(size_t)(144 + i0 + 0) * NC_];
            float q1 = Ac[(size_t)(10 + i0 + 1) * NC_] - Ac[(size_t)(144 + i0 + 1) * NC_];
            float q2 = Ac[(size_t)(10 + i0 + 2) * NC_] - Ac[(size_t)(144 + i0 + 2) * NC_];
            float q3 = Ac[(size_t)(10 + i0 + 3) * NC_] - Ac[(size_t)(144 + i0 + 3) * NC_];
#pragma unroll
            for (int k = 0; k < K_; k++) {
                float4 v = *(const float4*)&sm.sV[k][4 + i0];
                acc[k] = fmaf(v.x, q0, fmaf(v.y, q1, fmaf(v.z, q2, fmaf(v.w, q3, acc[k]))));
            }
        }
        {
            float q0 = Ac[(size_t)211 * NC_];
#pragma unroll
            for (int k = 0; k < K_; k++) acc[k] = fmaf(sm.sV[k][68], q0, acc[k]);
        }

        float m = -1e30f;
#pragma unroll
        for (int k = 0; k < K_; k++) {
            float v = base + acc[k];
            v = (v > 0.f) ? v : 0.2f * v;
            acc[k] = v;
            m = fmaxf(m, v);
        }
        float ssum = 0.f;
#pragma unroll
        for (int k = 0; k < K_; k++) { float e = __expf(acc[k] - m); acc[k] = e; ssum += e; }
        float inv = 1.f / ssum;

        int col; float addv; float sgn;
        if      (tid < 3)   { col = tid;       addv = 0.f;              sgn = 1.f; }
        else if (tid < 6)   { col = 0;         addv = sm.sF[61 + tid];  sgn = 0.f; }
        else if (tid < 9)   { col = tid - 6;   addv = sm.sF[58 + tid];  sgn = -1.f; }
        else if (tid == 9)  { col = 3;         addv = 0.f;              sgn = 1.f; }
        else if (tid < 74)  { col = tid - 6;   addv = 0.f;              sgn = 1.f; }
        else if (tid < 77)  { col = 0;         addv = sm.sGD[tid - 74]; sgn = 0.f; }
        else if (tid < 144) { col = 0;         addv = sm.sF[tid - 77];  sgn = 0.f; }
        else if (tid < 208) { col = tid - 140; addv = sm.sF[tid - 144]; sgn = -1.f; }
        else if (tid < 211) { col = 0;         addv = sm.sF[tid - 144] - sm.sGD[tid - 208]; sgn = 0.f; }
        else                { col = 68;        addv = 0.f;              sgn = 1.f; }
        float s = 0.f;
#pragma unroll
        for (int k = 0; k < K_; k++) s += acc[k] * sm.sV[k][col];
        sm.sPool[tid] = addv + sgn * (s * inv);
    }
    __syncthreads();

    // ph6: out = pooled @ w1^T + b1, stored transposed (B, 128, 1024) f32
    if (tid < CO_) {
        const float* w = W1 + (size_t)tid * NC_;
        float accO = 0.f;
        for (int c = 0; c < NC_; c += 4) {
            float4 wv = *(const float4*)(w + c);
            accO += wv.x * sm.sPool[c] + wv.y * sm.sPool[c + 1] + wv.z * sm.sPool[c + 2] + wv.w * sm.sPool[c + 3];
        }
        accO += B1[tid];
        out1[((size_t)b * CO_ + tid) * NP_ + n] = accO;
    }
}

// ---------------------------------------------------------------------------
// Mega-kernel: first 8 ticket-takers run FPS (guaranteed resident => no
// deadlock regardless of dispatch order); the rest are fused blocks that
// acquire-wait on per-batch progress. Outputs identical to the two-kernel
// version for any scheduling.
// ---------------------------------------------------------------------------
__global__ __launch_bounds__(256) void mega_kernel(
    const float* __restrict__ xyz, const float* __restrict__ feat,
    const float* __restrict__ A, const float* __restrict__ W1,
    const float* __restrict__ B1,
    int* hdr, int* fpsIdx, float* out0, float* out1) {
    __shared__ MegaSm sm;
    __shared__ int sRole;
    if (threadIdx.x == 0) sRole = atomicAdd(&hdr[0], 1);
    __syncthreads();
    int role = sRole;
    int* progress = hdr + 1;   // 8 ints

    if (role < B_) {
        __builtin_amdgcn_s_setprio(3);   // keep fps issue priority over cohabiting fused waves
        fps_role(role, xyz, fpsIdx, out0, progress, sm.f);
        __builtin_amdgcn_s_setprio(0);
    } else {
        fused_role(role - B_, feat, xyz, out0, fpsIdx, progress, A, W1, B1, out1, sm.u);
    }
}

// ---------------------------------------------------------------------------
extern "C" void kernel_launch(void* const* d_in, const int* in_sizes, int n_in,
                              void* d_out, int out_size, void* d_ws, size_t ws_size,
                              hipStream_t stream) {
    (void)in_sizes; (void)n_in; (void)out_size; (void)ws_size;
    const float* xyz      = (const float*)d_in[0];
    const float* features = (const float*)d_in[1];
    const float* A        = (const float*)d_in[2];
    const float* W1       = (const float*)d_in[3];
    const float* B1       = (const float*)d_in[4];
    float* out0 = (float*)d_out;                     // new_xyz (B,1024,3) f32
    float* out1 = out0 + (size_t)B_ * NP_ * 3;       // features (B,128,1024) f32

    int* hdr    = (int*)d_ws;                        // [0]=ticket, [1..8]=progress
    int* fpsIdx = hdr + 16;                          // B*NP ints

    hipMemsetAsync(d_ws, 0, 64, stream);             // reset ticket + progress each call
    mega_kernel<<<dim3(B_ * NP_ + B_), dim3(256), 0, stream>>>(
        xyz, features, A, W1, B1, hdr, fpsIdx, out0, out1);
}